// Round 10
// baseline (106.314 us; speedup 1.0000x reference)
//
#include <hip/hip_runtime.h>
#include <hip/hip_bf16.h>

#define NROWS 262144
#define NB1 2048           // k1 blocks
#define RPB 128            // rows per k1 block (4 waves x 32 rows, single pass)
// exp(x*0.125) == exp2(x * 0.125*log2(e))
#define CL 0.18033688011112042f

typedef __attribute__((ext_vector_type(8))) short s8v;   // 8 bf16 (4 VGPRs)
typedef __attribute__((ext_vector_type(4))) short s4h;   // 4 bf16 (2 VGPRs)
typedef __attribute__((ext_vector_type(4))) float f4v;   // float4 / MFMA acc

__device__ __forceinline__ short f2bf(float x) {         // RNE float->bf16 bits
    unsigned u = __float_as_uint(x);
    u += 0x7FFF + ((u >> 16) & 1);
    return (short)(u >> 16);
}

// sum over each contiguous 16-lane group via DPP (VALU pipe only)
__device__ __forceinline__ float dpp_red16(float x) {
    int t;
    t = __builtin_amdgcn_update_dpp(0, __float_as_int(x), 0xB1,  0xF, 0xF, true); // quad xor1
    x += __int_as_float(t);
    t = __builtin_amdgcn_update_dpp(0, __float_as_int(x), 0x4E,  0xF, 0xF, true); // quad xor2
    x += __int_as_float(t);
    t = __builtin_amdgcn_update_dpp(0, __float_as_int(x), 0x141, 0xF, 0xF, true); // half_mirror
    x += __int_as_float(t);
    t = __builtin_amdgcn_update_dpp(0, __float_as_int(x), 0x140, 0xF, 0xF, true); // mirror
    x += __int_as_float(t);
    return x;
}

// K1: BARRIER-FREE hot path. Each of 4 waves independently: loads its own 32
// rows of K,V,Q (24 x dwordx4, one batch), row-softmax (dpp_red16), packs
// bf16 kk/V into wave-private LDS slices (wave-local lgkmcnt only, no
// __syncthreads), reads its own MFMA fragments back, and accumulates the
// FULL 64x64 ctx^T over its rows into a 4x4-tile register accumulator.
// Deterministic fixed-order cross-wave tile reduce at the end only.
__global__ __launch_bounds__(256, 4) void k1_stats(const float* __restrict__ Q,
                                                   const float* __restrict__ K,
                                                   const float* __restrict__ V,
                                                   float* __restrict__ ctx_part,  // [NB1][c][v]
                                                   float* __restrict__ qs_part)   // [NB1][64]
{
    const int tid  = threadIdx.x;
    const int lane = tid & 63;
    const int wid  = tid >> 6;          // 4 waves
    const int m    = lane & 15;         // col-quad (cols 4m..4m+3)
    const int g    = lane >> 4;         // row-in-quad / k-group
    const size_t r0 = (size_t)blockIdx.x * RPB + wid * 32;   // wave's 32 rows

    // wave-private slices; 132B row stride -> conflict-free u16 col reads
    __shared__ __attribute__((aligned(16))) ushort kkL[4][32][66];  // 16.9 KB
    __shared__ __attribute__((aligned(16))) ushort vvL[4][32][66];  // 16.9 KB
    __shared__ float qsl[4][64];

    const f4v* K4 = (const f4v*)K;
    const f4v* V4 = (const f4v*)V;
    const f4v* Q4 = (const f4v*)Q;

    // ---- one batch of 24 independent dwordx4 loads (deep MLP, no barriers)
    f4v k4[8], v4[8], q4[8];
#pragma unroll
    for (int i = 0; i < 8; ++i) k4[i] = K4[(r0 + i * 4 + g) * 16 + m];
#pragma unroll
    for (int i = 0; i < 8; ++i) v4[i] = V4[(r0 + i * 4 + g) * 16 + m];
#pragma unroll
    for (int i = 0; i < 8; ++i) q4[i] = Q4[(r0 + i * 4 + g) * 16 + m];

    // ---- Q colsum partials (lane covers cols 4m..4m+3)
    f4v qs4 = {0.f, 0.f, 0.f, 0.f};
#pragma unroll
    for (int i = 0; i < 8; ++i) {
        qs4[0] += exp2f(q4[i][0] * CL); qs4[1] += exp2f(q4[i][1] * CL);
        qs4[2] += exp2f(q4[i][2] * CL); qs4[3] += exp2f(q4[i][3] * CL);
    }
#pragma unroll
    for (int c = 0; c < 4; ++c) {       // combine 4 row-groups sharing col-quad m
        qs4[c] += __shfl_xor(qs4[c], 16);
        qs4[c] += __shfl_xor(qs4[c], 32);
    }
    if (g == 0) *(f4v*)&qsl[wid][4 * m] = qs4;

    // ---- K row softmax (args bounded, no max): row = 16-lane group
    f4v e4[8]; float rs[8];
#pragma unroll
    for (int i = 0; i < 8; ++i) {
        e4[i][0] = exp2f(k4[i][0] * CL); e4[i][1] = exp2f(k4[i][1] * CL);
        e4[i][2] = exp2f(k4[i][2] * CL); e4[i][3] = exp2f(k4[i][3] * CL);
    }
#pragma unroll
    for (int i = 0; i < 8; ++i)
        rs[i] = dpp_red16((e4[i][0] + e4[i][1]) + (e4[i][2] + e4[i][3]));

    // ---- pack bf16 into wave-private LDS (local row 4i+g, cols 4m..4m+3)
#pragma unroll
    for (int i = 0; i < 8; ++i) {
        const float inv = __builtin_amdgcn_rcpf(rs[i]);
        s4h kp = s4h{f2bf(e4[i][0] * inv), f2bf(e4[i][1] * inv),
                     f2bf(e4[i][2] * inv), f2bf(e4[i][3] * inv)};
        s4h vp = s4h{f2bf(v4[i][0]), f2bf(v4[i][1]),
                     f2bf(v4[i][2]), f2bf(v4[i][3])};
        *(s4h*)&kkL[wid][4 * i + g][4 * m] = kp;
        *(s4h*)&vvL[wid][4 * i + g][4 * m] = vp;
    }

    // ---- fragments (wave-private; compiler inserts the wave-local lgkmcnt)
    // frag element e <-> k-row 8g+e; tile row index = m
    s8v bf[4], af[4];
#pragma unroll
    for (int p = 0; p < 4; ++p)
#pragma unroll
        for (int e = 0; e < 8; ++e) {
            bf[p][e] = (short)kkL[wid][8 * g + e][16 * p + m];
            af[p][e] = (short)vvL[wid][8 * g + e][16 * p + m];
        }

    // ---- 16 MFMAs: acc[p][va] = ctx^T tile (c-panel p, v-panel va)
    f4v acc[4][4];
#pragma unroll
    for (int p = 0; p < 4; ++p)
#pragma unroll
        for (int va = 0; va < 4; ++va) {
            acc[p][va] = f4v{0.f, 0.f, 0.f, 0.f};
            acc[p][va] = __builtin_amdgcn_mfma_f32_16x16x32_bf16(af[va], bf[p],
                                                                 acc[p][va], 0, 0, 0);
        }

    // ---- deterministic cross-wave tile reduce (reuse kkL as fp32 buffer)
    float* red = (float*)&kkL[0][0][0];   // 16 KB needed, kkL = 16.9 KB
    __syncthreads();                       // all frag reads done
    if (wid == 0) {
#pragma unroll
        for (int p = 0; p < 4; ++p)
#pragma unroll
            for (int va = 0; va < 4; ++va)
                *(f4v*)&red[(16 * p + m) * 64 + 16 * va + 4 * g] = acc[p][va];
    }
    __syncthreads();
#pragma unroll
    for (int w = 1; w < 4; ++w) {
        if (wid == w) {
#pragma unroll
            for (int p = 0; p < 4; ++p)
#pragma unroll
                for (int va = 0; va < 4; ++va) {
                    f4v* a = (f4v*)&red[(16 * p + m) * 64 + 16 * va + 4 * g];
                    *a += acc[p][va];
                }
        }
        __syncthreads();
    }
    // coalesced block output: D[c][v] (c row-major), 16 floats/thread
#pragma unroll
    for (int j = 0; j < 4; ++j) {
        const int e = tid + 256 * j;
        *(f4v*)&ctx_part[(size_t)blockIdx.x * 4096 + 4 * e] = *(const f4v*)&red[4 * e];
    }
    if (tid < 64)
        qs_part[blockIdx.x * 64 + tid] =
            (qsl[0][tid] + qsl[1][tid]) + (qsl[2][tid] + qsl[3][tid]);
}

// K2: one block per column c. float4 reduce of ctx partials + Q colsum
// partials; fold 1/colsum; emit ctx' TRANSPOSED bf16: ctxfT[v][c].
__global__ __launch_bounds__(256) void k2(const float* __restrict__ ctx_part,
                                          const float* __restrict__ qs_part,
                                          ushort* __restrict__ ctxfT) {
    const int c = blockIdx.x;        // 64 blocks
    const int tid = threadIdx.x;
    const int bg = tid >> 4, vq = tid & 15;
    __shared__ f4v  red[16][16];
    __shared__ float qred[4][64];
    f4v s = {0.f, 0.f, 0.f, 0.f};
    for (int b = bg; b < NB1; b += 16)
        s += *(const f4v*)&ctx_part[(size_t)b * 4096 + c * 64 + vq * 4];
    float q = 0.f;
    for (int b = tid; b < NB1; b += 256) q += qs_part[b * 64 + c];
    red[bg][vq] = s;
    qred[tid >> 6][tid & 63] = q;
    __syncthreads();
    if (tid < 64) {
        float t = 0.f;
#pragma unroll
        for (int b = 0; b < 16; ++b) t += red[b][tid >> 2][tid & 3];
        float qv = (qred[0][tid] + qred[1][tid]) + (qred[2][tid] + qred[3][tid]);
        qv = dpp_red16(qv);
        qv += __shfl_xor(qv, 16);
        qv += __shfl_xor(qv, 32);
        ctxfT[tid * 64 + c] = (ushort)f2bf(t * __builtin_amdgcn_rcpf(qv));
    }
}

// K3: out = q~ @ ctx' via MFMA with swapped operands (A=ctx'^T frags, B=q~
// frags) so D = out^T frags give 4 consecutive out cols/lane -> dwordx4.
__global__ __launch_bounds__(256) void k3_out(const float* __restrict__ Q,
                                              const ushort* __restrict__ ctxfT,
                                              float* __restrict__ out) {
    const int tid  = threadIdx.x;
    const int lane = tid & 63;
    const int wid  = tid >> 6;      // 4 waves
    const int li = lane & 15, g = lane >> 4;

    s8v ct[4][2];                   // A frags: ctxfT[va*16+li][32ks+8g .. +7]
#pragma unroll
    for (int va = 0; va < 4; ++va)
#pragma unroll
        for (int ks = 0; ks < 2; ++ks)
            ct[va][ks] = *(const s8v*)((const char*)ctxfT +
                            2 * ((va * 16 + li) * 64 + 32 * ks + 8 * g));

#pragma unroll
    for (int t = 0; t < 4; ++t) {
        const int rb  = blockIdx.x * 256 + t * 64 + wid * 16;
        const int row = rb + li;
        const f4v* qp = (const f4v*)(Q + (size_t)row * 64);
        f4v q0 = qp[2 * g], q1 = qp[2 * g + 1];          // cols 8g..+7   (ks=0)
        f4v q2 = qp[8 + 2 * g], q3 = qp[8 + 2 * g + 1];  // cols 32+8g..+7 (ks=1)
        s8v b0, b1;                 // B frags: q~[row][32ks+8g .. +7]
#pragma unroll
        for (int e = 0; e < 4; ++e) {
            b0[e]     = f2bf(exp2f(q0[e] * CL));
            b0[e + 4] = f2bf(exp2f(q1[e] * CL));
            b1[e]     = f2bf(exp2f(q2[e] * CL));
            b1[e + 4] = f2bf(exp2f(q3[e] * CL));
        }
#pragma unroll
        for (int va = 0; va < 4; ++va) {
            f4v a = {0.f, 0.f, 0.f, 0.f};
            a = __builtin_amdgcn_mfma_f32_16x16x32_bf16(ct[va][0], b0, a, 0, 0, 0);
            a = __builtin_amdgcn_mfma_f32_16x16x32_bf16(ct[va][1], b1, a, 0, 0, 0);
            *(f4v*)&out[(size_t)row * 64 + va * 16 + 4 * g] = a;   // 4 consecutive v
        }
    }
}

extern "C" void kernel_launch(void* const* d_in, const int* in_sizes, int n_in,
                              void* d_out, int out_size, void* d_ws, size_t ws_size,
                              hipStream_t stream) {
    const float* Q = (const float*)d_in[0];
    const float* K = (const float*)d_in[1];
    const float* V = (const float*)d_in[2];
    float* out = (float*)d_out;

    float* w = (float*)d_ws;
    size_t off = 0;
    float*  qs_part = w + off;              off += (size_t)NB1 * 64;
    ushort* ctxfT   = (ushort*)(w + off);   off += 2048;   // 4096 bf16 = 8KB
    float* ctx_part;
    const size_t need = (off + (size_t)NB1 * 4096) * sizeof(float);
    if (ws_size >= need) {
        ctx_part = w + off;
    } else {
        // 32 MB of partials live in d_out scratch (k3 fully overwrites later)
        ctx_part = out;
    }

    k1_stats<<<NB1, 256, 0, stream>>>(Q, K, V, ctx_part, qs_part);
    k2<<<64, 256, 0, stream>>>(ctx_part, qs_part, ctxfT);
    k3_out<<<NROWS / 256, 256, 0, stream>>>(Q, ctxfT, out);
}